// Round 3
// baseline (386.552 us; speedup 1.0000x reference)
//
#include <hip/hip_runtime.h>
#include <hip/hip_bf16.h>

#define T_STEPS 100
#define BATCH   256
#define IN_DIM  784
#define HID_DIM 1024
#define OUT_DIM 10
#define M_ROWS  (T_STEPS * BATCH)   // 25600
#define KPAD    800                 // IN_DIM padded to multiple of 32
#define NT      25                  // K tiles of 32
#define ASTG    4096                // elements per A stage (8 KB)
#define DECAY   0.6f
#define THRESH  0.9f

typedef __attribute__((ext_vector_type(8))) short bf16x8;
typedef __attribute__((ext_vector_type(4))) float f32x4;

// pack 8 fp32 (two float4) -> 8 bf16 (uint4) by truncation; exact for {0,1}
#define PACK8(dstp, v0, v1)                                                                        \
    {                                                                                              \
        unsigned int p0 = __builtin_amdgcn_perm(__builtin_bit_cast(unsigned int, (v0).y),          \
                                                __builtin_bit_cast(unsigned int, (v0).x), 0x07060302u); \
        unsigned int p1 = __builtin_amdgcn_perm(__builtin_bit_cast(unsigned int, (v0).w),          \
                                                __builtin_bit_cast(unsigned int, (v0).z), 0x07060302u); \
        unsigned int p2 = __builtin_amdgcn_perm(__builtin_bit_cast(unsigned int, (v1).y),          \
                                                __builtin_bit_cast(unsigned int, (v1).x), 0x07060302u); \
        unsigned int p3 = __builtin_amdgcn_perm(__builtin_bit_cast(unsigned int, (v1).w),          \
                                                __builtin_bit_cast(unsigned int, (v1).z), 0x07060302u); \
        *(uint4*)(dstp) = make_uint4(p0, p1, p2, p3);                                              \
    }

// async global->LDS, 16B per lane, linear wave-contiguous LDS dest
#define GLL(g, l)                                                                                  \
    __builtin_amdgcn_global_load_lds((const __attribute__((address_space(1))) void*)(g),           \
                                     (__attribute__((address_space(3))) void*)(l), 16, 0, 0)

// ---------------------------------------------------------------------------
// W1 split-transpose body (shared by prep / prep_small):
// W1[784][1024] fp32 -> Th[1024][800] bf16 (hi), Tl[1024][800] bf16 (lo).
// ---------------------------------------------------------------------------
__device__ __forceinline__ void w1_split_body(const float* __restrict__ W1,
                                              unsigned short* __restrict__ Th,
                                              unsigned short* __restrict__ Tl,
                                              int b2, int t,
                                              unsigned short lh[32][33],
                                              unsigned short ll[32][33]) {
    const int nb = (b2 & 31) * 32;
    const int kb = (b2 >> 5) * 32;
    const int ln = t & 31, lk = t >> 5;
    #pragma unroll
    for (int i = 0; i < 4; ++i) {
        const int k = kb + lk + i * 8;
        const float w = (k < IN_DIM) ? W1[(size_t)k * HID_DIM + nb + ln] : 0.f;
        __hip_bfloat16 h = __float2bfloat16(w);
        float hf = __bfloat162float(h);
        __hip_bfloat16 l = __float2bfloat16(w - hf);
        lh[lk + i * 8][ln] = __builtin_bit_cast(unsigned short, h);
        ll[lk + i * 8][ln] = __builtin_bit_cast(unsigned short, l);
    }
    __syncthreads();
    const int o_n = t >> 3;
    const int o_k = (t & 7) * 4;
    ushort4 vh, vl;
    vh.x = lh[o_k + 0][o_n]; vh.y = lh[o_k + 1][o_n];
    vh.z = lh[o_k + 2][o_n]; vh.w = lh[o_k + 3][o_n];
    vl.x = ll[o_k + 0][o_n]; vl.y = ll[o_k + 1][o_n];
    vl.z = ll[o_k + 2][o_n]; vl.w = ll[o_k + 3][o_n];
    *(ushort4*)&Th[(size_t)(nb + o_n) * KPAD + kb + o_k] = vh;
    *(ushort4*)&Tl[(size_t)(nb + o_n) * KPAD + kb + o_k] = vl;
}

// ---------------------------------------------------------------------------
// prep (big-workspace path): X->bf16, W1 split, outu zero — one launch.
// ---------------------------------------------------------------------------
__global__ __launch_bounds__(256) void prep(const float* __restrict__ X,
                                            const float* __restrict__ W1,
                                            unsigned short* __restrict__ Xb,
                                            unsigned short* __restrict__ Th,
                                            unsigned short* __restrict__ Tl,
                                            float* __restrict__ outu) {
    __shared__ unsigned short lh[32][33];
    __shared__ unsigned short ll[32][33];
    const int bid = blockIdx.x;
    const int t   = threadIdx.x;

    if (bid < 10000) {
        const int gid = bid * 256 + t;           // 0 .. 2,559,999
        const int r   = gid / 100;
        const int c   = gid - r * 100;
        unsigned short* dst = Xb + (size_t)r * KPAD + c * 8;
        if (c < 98) {
            const float* s = X + (size_t)r * IN_DIM + c * 8;
            float4 v0 = *(const float4*)s, v1 = *(const float4*)(s + 4);
            PACK8(dst, v0, v1);
        } else {
            *(uint4*)dst = make_uint4(0u, 0u, 0u, 0u);
        }
    } else if (bid < 10800) {
        w1_split_body(W1, Th, Tl, bid - 10000, t, lh, ll);
    } else {
        float4* p = (float4*)outu;
        p[(bid - 10800) * 256 + t] = make_float4(0.f, 0.f, 0.f, 0.f);
    }
}

// prep_small (fallback path): W1 split + outu zero only (proven 3.3 MB ws use)
__global__ __launch_bounds__(256) void prep_small(const float* __restrict__ W1,
                                                  unsigned short* __restrict__ Th,
                                                  unsigned short* __restrict__ Tl,
                                                  float* __restrict__ outu) {
    __shared__ unsigned short lh[32][33];
    __shared__ unsigned short ll[32][33];
    const int bid = blockIdx.x;
    const int t   = threadIdx.x;
    if (bid < 800) {
        w1_split_body(W1, Th, Tl, bid, t, lh, ll);
    } else {
        float4* p = (float4*)outu;
        p[(bid - 800) * 256 + t] = make_float4(0.f, 0.f, 0.f, 0.f);
    }
}

// ---------------------------------------------------------------------------
// gemm1_breg: C[25600 x 1024] = Xb @ (Th + Tl), all-bf16 operands.
// 128x128 tile, BK=32, 4 waves x 64x64. A: global_load_lds into a 4-stage
// 8 KB ring (32 KB LDS), depth-3 prefetch, XOR-chunk-swizzled source + read.
// B (Th/Tl, 3.2 MB total -> L2-resident): loaded DIRECTLY to registers per
// wave as uint4 (the exact 16 contiguous bf16 bytes the old LDS path read --
// bit-identical), double-buffered with static register names.
// One raw s_barrier per iter. Per-iter issue: [B(k+1) x8][A-GLL(k+3) x2];
// explicit vmcnt(12) at iter top pins <=12 outstanding (A(k) retired);
// compiler-inserted waits cover B-register readiness.
// ---------------------------------------------------------------------------
__global__ __launch_bounds__(256, 3) void gemm1_breg(const unsigned short* __restrict__ Xb,
                                                     const unsigned short* __restrict__ Th,
                                                     const unsigned short* __restrict__ Tl,
                                                     float* __restrict__ C) {
    __shared__ unsigned short smem[4 * ASTG];   // 32 KB

    const int tid = threadIdx.x;
    const int bid = blockIdx.x;
    const int xcd = bid & 7;
    const int j_  = bid >> 3;                  // 0..199
    const int m0  = (xcd * 25 + (j_ >> 3)) * 128;
    const int n0  = (j_ & 7) * 128;

    const int lane = tid & 63, wv = tid >> 6;
    const int wm   = (wv & 1) * 64, wn = (wv >> 1) * 64;
    const int ml   = lane & 15, quad = lane >> 4;

    // A staging: thread t covers chunk t (rows 0..63) and t+256 (rows 64..127)
    const int row  = tid >> 2;                 // 0..63
    const int slot = tid & 3;
    const int sOff = (slot ^ ((row >> 1) & 3)) * 8;   // f(row+64)==f(row)

    const unsigned short* gA0 = Xb + (size_t)(m0 + row)      * KPAD + sOff;
    const unsigned short* gA1 = Xb + (size_t)(m0 + row + 64) * KPAD + sOff;

    // B fragment pointers (per wave, per n-frag): 16 contiguous bf16 at
    // row n, k-chunk quad — identical bytes to the old LDS fragment.
    const unsigned short* pH[4];
    const unsigned short* pL[4];
    #pragma unroll
    for (int j = 0; j < 4; ++j) {
        const int n = n0 + wn + j * 16 + ml;
        pH[j] = Th + (size_t)n * KPAD + quad * 8;
        pL[j] = Tl + (size_t)n * KPAD + quad * 8;
    }

    f32x4 acc[4][4];
    #pragma unroll
    for (int i = 0; i < 4; ++i)
        #pragma unroll
        for (int j = 0; j < 4; ++j)
            acc[i][j] = (f32x4){0.f, 0.f, 0.f, 0.f};

    // A fragment LDS element offsets (swizzled read = inverse of staged source)
    int offA[4];
    #pragma unroll
    for (int i = 0; i < 4; ++i) {
        const int m = wm + i * 16 + ml;
        offA[i] = m * 32 + ((quad ^ ((m >> 1) & 3)) * 8);
    }

    auto stageA = [&](int it) __attribute__((always_inline)) {
        unsigned short* b_ = smem + (it & 3) * ASTG;
        const int ko = it * 32;
        GLL(gA0 + ko, b_ + tid * 8);
        GLL(gA1 + ko, b_ + 2048 + tid * 8);
    };

    auto loadB = [&](uint4 (&h)[4], uint4 (&l)[4], int it) __attribute__((always_inline)) {
        const int ko = it * 32;
        #pragma unroll
        for (int j = 0; j < 4; ++j) {
            h[j] = *(const uint4*)(pH[j] + ko);
            l[j] = *(const uint4*)(pL[j] + ko);
        }
    };

    uint4 b0h[4], b0l[4], b1h[4], b1l[4];

    auto iter = [&](int k, uint4 (&ch)[4], uint4 (&cl)[4],
                    uint4 (&nh)[4], uint4 (&nl)[4]) __attribute__((always_inline)) {
        // A(k) GLLs are >=12 ops old; <=12 outstanding => A(k) retired (in-order).
        asm volatile("s_waitcnt vmcnt(12)" ::: "memory");
        __builtin_amdgcn_s_barrier();           // raw: no auto vmcnt(0) drain
        asm volatile("" ::: "memory");

        if (k + 1 < NT) loadB(nh, nl, k + 1);   // 8 VMEM (L2-resident B)
        if (k + 3 < NT) stageA(k + 3);          // 2 GLL into slot (k+3)&3

        const unsigned short* base = smem + (k & 3) * ASTG;
        bf16x8 af[4];
        #pragma unroll
        for (int i = 0; i < 4; ++i)
            af[i] = *(const bf16x8*)&base[offA[i]];

        __builtin_amdgcn_s_setprio(1);
        #pragma unroll
        for (int i = 0; i < 4; ++i)
            #pragma unroll
            for (int j = 0; j < 4; ++j) {
                acc[i][j] = __builtin_amdgcn_mfma_f32_16x16x32_bf16(
                    af[i], __builtin_bit_cast(bf16x8, ch[j]), acc[i][j], 0, 0, 0);
                acc[i][j] = __builtin_amdgcn_mfma_f32_16x16x32_bf16(
                    af[i], __builtin_bit_cast(bf16x8, cl[j]), acc[i][j], 0, 0, 0);
            }
        __builtin_amdgcn_s_setprio(0);
    };

    // prologue: A(0),A(1) in flight, B(0) in flight, A(2) in flight
    stageA(0);
    stageA(1);
    loadB(b0h, b0l, 0);
    stageA(2);

    // 12 pairs (iters 0..23) + tail iter 24; B buffers swap statically
    for (int k = 0; k + 1 < NT; k += 2) {
        iter(k,     b0h, b0l, b1h, b1l);
        iter(k + 1, b1h, b1l, b0h, b0l);
    }
    iter(NT - 1, b0h, b0l, b1h, b1l);

    // epilogue: C/D layout col=lane&15, row=quad*4+reg
    #pragma unroll
    for (int i = 0; i < 4; ++i)
        #pragma unroll
        for (int j = 0; j < 4; ++j) {
            const int r0 = m0 + wm + i * 16 + quad * 4;
            const int c0 = n0 + wn + j * 16 + ml;
            #pragma unroll
            for (int r = 0; r < 4; ++r)
                C[(size_t)(r0 + r) * HID_DIM + c0] = acc[i][j][r];
        }
}

// ---------------------------------------------------------------------------
// gemm1_fallback: harness-verified R0 kernel (fp32 X, PACK8 in-kernel).
// Used only when ws is too small for Xb.
// ---------------------------------------------------------------------------
__global__ __launch_bounds__(256, 3) void gemm1_fallback(const float* __restrict__ X,
                                                         const unsigned short* __restrict__ Th,
                                                         const unsigned short* __restrict__ Tl,
                                                         float* __restrict__ C) {
    __shared__ unsigned short As[128 * 32];
    __shared__ unsigned short Bhs[128 * 32];
    __shared__ unsigned short Bls[128 * 32];

    const int tid = threadIdx.x;
    const int bid = blockIdx.x;
    const int xcd = bid & 7;
    const int j_  = bid >> 3;
    const int m0  = (xcd * 25 + (j_ >> 3)) * 128;
    const int n0  = (j_ & 7) * 128;

    const int lane = tid & 63, wv = tid >> 6;
    const int wm   = (wv & 1) * 64, wn = (wv >> 1) * 64;
    const int ml   = lane & 15, quad = lane >> 4;

    const int sr = tid >> 2;
    const int sc = tid & 3;
    const int f0 = (sr >> 1) & 3;
    const int w0 = sr * 32 + ((sc ^ f0) * 8);
    const int w1 = (sr + 64) * 32 + ((sc ^ f0) * 8);

    const float*          Xa = X  + (size_t)(m0 + sr)      * IN_DIM + sc * 8;
    const float*          Xc = X  + (size_t)(m0 + sr + 64) * IN_DIM + sc * 8;
    const unsigned short* Ha = Th + (size_t)(n0 + sr)      * KPAD   + sc * 8;
    const unsigned short* Hb = Th + (size_t)(n0 + sr + 64) * KPAD   + sc * 8;
    const unsigned short* La = Tl + (size_t)(n0 + sr)      * KPAD   + sc * 8;
    const unsigned short* Lb = Tl + (size_t)(n0 + sr + 64) * KPAD   + sc * 8;

    f32x4 acc[4][4];
    #pragma unroll
    for (int i = 0; i < 4; ++i)
        #pragma unroll
        for (int j = 0; j < 4; ++j)
            acc[i][j] = (f32x4){0.f, 0.f, 0.f, 0.f};

    float4 xa0 = *(const float4*)&Xa[0], xa1 = *(const float4*)&Xa[4];
    float4 xb0 = *(const float4*)&Xc[0], xb1 = *(const float4*)&Xc[4];
    uint4  vh0 = *(const uint4*)&Ha[0],  vh1 = *(const uint4*)&Hb[0];
    uint4  vl0 = *(const uint4*)&La[0],  vl1 = *(const uint4*)&Lb[0];
    PACK8(&As[w0], xa0, xa1);
    PACK8(&As[w1], xb0, xb1);
    *(uint4*)&Bhs[w0] = vh0;  *(uint4*)&Bhs[w1] = vh1;
    *(uint4*)&Bls[w0] = vl0;  *(uint4*)&Bls[w1] = vl1;
    __syncthreads();

    for (int it = 0; it < NT; ++it) {
        bf16x8 af[4], bh[4], bl[4];
        #pragma unroll
        for (int i = 0; i < 4; ++i) {
            const int m = wm + i * 16 + ml;
            af[i] = *(const bf16x8*)&As[m * 32 + ((quad ^ ((m >> 1) & 3)) * 8)];
        }
        #pragma unroll
        for (int j = 0; j < 4; ++j) {
            const int n   = wn + j * 16 + ml;
            const int idx = n * 32 + ((quad ^ ((n >> 1) & 3)) * 8);
            bh[j] = *(const bf16x8*)&Bhs[idx];
            bl[j] = *(const bf16x8*)&Bls[idx];
        }

        const bool have_next = (it + 1 < NT);
        if (have_next) {
            const int kt = (it + 1) * 32;
            const int c0 = kt + sc * 8;
            const bool v0 = (c0 < IN_DIM), v1 = (c0 + 4 < IN_DIM);
            xa0 = v0 ? *(const float4*)&Xa[kt]     : make_float4(0.f, 0.f, 0.f, 0.f);
            xa1 = v1 ? *(const float4*)&Xa[kt + 4] : make_float4(0.f, 0.f, 0.f, 0.f);
            xb0 = v0 ? *(const float4*)&Xc[kt]     : make_float4(0.f, 0.f, 0.f, 0.f);
            xb1 = v1 ? *(const float4*)&Xc[kt + 4] : make_float4(0.f, 0.f, 0.f, 0.f);
            vh0 = *(const uint4*)&Ha[kt];  vh1 = *(const uint4*)&Hb[kt];
            vl0 = *(const uint4*)&La[kt];  vl1 = *(const uint4*)&Lb[kt];
        }

        #pragma unroll
        for (int i = 0; i < 4; ++i)
            #pragma unroll
            for (int j = 0; j < 4; ++j) {
                acc[i][j] = __builtin_amdgcn_mfma_f32_16x16x32_bf16(af[i], bh[j], acc[i][j], 0, 0, 0);
                acc[i][j] = __builtin_amdgcn_mfma_f32_16x16x32_bf16(af[i], bl[j], acc[i][j], 0, 0, 0);
            }

        __syncthreads();
        if (have_next) {
            PACK8(&As[w0], xa0, xa1);
            PACK8(&As[w1], xb0, xb1);
            *(uint4*)&Bhs[w0] = vh0;  *(uint4*)&Bhs[w1] = vh1;
            *(uint4*)&Bls[w0] = vl0;  *(uint4*)&Bls[w1] = vl1;
            __syncthreads();
        }
    }

    #pragma unroll
    for (int i = 0; i < 4; ++i)
        #pragma unroll
        for (int j = 0; j < 4; ++j) {
            const int r0 = m0 + wm + i * 16 + quad * 4;
            const int c0 = n0 + wn + j * 16 + ml;
            #pragma unroll
            for (int r = 0; r < 4; ++r)
                C[(size_t)(r0 + r) * HID_DIM + c0] = acc[i][j][r];
        }
}

// ---------------------------------------------------------------------------
// LIF1 fused with GEMM2 scatter. float2/thread: 131072 threads = 2 waves/SIMD
// for better latency overlap of the serial t-scan. Rare-spike atomic scatter.
// ---------------------------------------------------------------------------
__global__ __launch_bounds__(256) void lif1_fused(float* __restrict__ hid,
                                                  const float* __restrict__ W2,
                                                  float* __restrict__ outu) {
    const int idx = blockIdx.x * blockDim.x + threadIdx.x;   // 0..131071
    float2* h2 = (float2*)hid;
    const int stride2 = (BATCH * HID_DIM) / 2;               // 131072
    const int b  = idx >> 9;
    const int h0 = (idx * 2) & 1023;

    float2 mem = make_float2(0.f, 0.f);
    float2 u[4];
    #pragma unroll
    for (int c = 0; c < 4; ++c) u[c] = h2[c * stride2 + idx];

    for (int t = 0; t < T_STEPS; t += 4) {
        float2 nu[4];
        if (t + 4 < T_STEPS) {
            #pragma unroll
            for (int c = 0; c < 4; ++c) nu[c] = h2[(t + 4 + c) * stride2 + idx];
        }
        #pragma unroll
        for (int c = 0; c < 4; ++c) {
            float2 uu = u[c];
            float2 s;
            mem.x = mem.x * DECAY + uu.x; s.x = (mem.x >= THRESH) ? 1.f : 0.f; mem.x -= s.x * THRESH;
            mem.y = mem.y * DECAY + uu.y; s.y = (mem.y >= THRESH) ? 1.f : 0.f; mem.y -= s.y * THRESH;
            h2[(t + c) * stride2 + idx] = s;
            if (s.x + s.y > 0.f) {                           // ~never taken
                float* od = outu + (size_t)(t + c) * (BATCH * OUT_DIM) + b * OUT_DIM;
                #pragma unroll
                for (int e = 0; e < 2; ++e) {
                    const float sv = (&s.x)[e];
                    if (sv != 0.f) {
                        const float* w = W2 + (size_t)(h0 + e) * OUT_DIM;
                        #pragma unroll
                        for (int o = 0; o < OUT_DIM; ++o) atomicAdd(&od[o], w[o]);
                    }
                }
            }
        }
        #pragma unroll
        for (int c = 0; c < 4; ++c) u[c] = nu[c];
    }
}

// ---------------------------------------------------------------------------
// LIF2: scan output membranes in place; 4-deep prefetch hides serial latency.
// ---------------------------------------------------------------------------
__global__ __launch_bounds__(256) void lif2(float* __restrict__ outp) {
    const int n = blockIdx.x * blockDim.x + threadIdx.x;
    const int stride = BATCH * OUT_DIM;                      // 2560
    if (n >= stride) return;
    float mem = 0.f;
    float u[4];
    #pragma unroll
    for (int c = 0; c < 4; ++c) u[c] = outp[c * stride + n];
    for (int t = 0; t < T_STEPS; t += 4) {
        float nu[4];
        if (t + 4 < T_STEPS) {
            #pragma unroll
            for (int c = 0; c < 4; ++c) nu[c] = outp[(t + 4 + c) * stride + n];
        }
        #pragma unroll
        for (int c = 0; c < 4; ++c) {
            mem = mem * DECAY + u[c];
            float s = (mem >= THRESH) ? 1.f : 0.f;
            mem -= s * THRESH;
            outp[(t + c) * stride + n] = s;
        }
        #pragma unroll
        for (int c = 0; c < 4; ++c) u[c] = nu[c];
    }
}

extern "C" void kernel_launch(void* const* d_in, const int* in_sizes, int n_in,
                              void* d_out, int out_size, void* d_ws, size_t ws_size,
                              hipStream_t stream) {
    const float* x  = (const float*)d_in[0];   // [T, B, I]
    const float* W1 = (const float*)d_in[1];   // [I, H]
    const float* W2 = (const float*)d_in[2];   // [H, O]
    float* out  = (float*)d_out;
    float* hid  = out;                                    // [T*B, H]
    float* outu = out + (size_t)M_ROWS * HID_DIM;         // [T*B, O]

    unsigned short* Th = (unsigned short*)d_ws;           // [1024][800] bf16 (1.6 MB)
    unsigned short* Tl = Th + (size_t)HID_DIM * KPAD;     // [1024][800] bf16 (1.6 MB)
    unsigned short* Xb = Tl + (size_t)HID_DIM * KPAD;     // [25600][800] bf16 (41 MB)

    const size_t ws_needed_big =
        (size_t)2 * HID_DIM * KPAD * sizeof(unsigned short) +
        (size_t)M_ROWS * KPAD * sizeof(unsigned short);   // 44.24 MB

    if (ws_size >= ws_needed_big) {
        // fast path: all-bf16 GEMM, A via LDS ring, B direct-to-register
        prep<<<11050, 256, 0, stream>>>(x, W1, Xb, Th, Tl, outu);
        gemm1_breg<<<1600, 256, 0, stream>>>(Xb, Th, Tl, hid);
    } else {
        // proven-safe path: 3.3 MB workspace only
        prep_small<<<1050, 256, 0, stream>>>(W1, Th, Tl, outu);
        gemm1_fallback<<<1600, 256, 0, stream>>>(x, Th, Tl, hid);
    }

    lif1_fused<<<(BATCH * HID_DIM / 2) / 256, 256, 0, stream>>>(hid, W2, outu);

    lif2<<<(BATCH * OUT_DIM + 255) / 256, 256, 0, stream>>>(outu);
}

// Round 4
// 276.215 us; speedup vs baseline: 1.3995x; 1.3995x over previous
//
#include <hip/hip_runtime.h>
#include <hip/hip_bf16.h>

#define T_STEPS 100
#define BATCH   256
#define IN_DIM  784
#define HID_DIM 1024
#define OUT_DIM 10
#define M_ROWS  (T_STEPS * BATCH)   // 25600
#define KPAD    800                 // IN_DIM padded to multiple of 32
#define NT      25                  // K tiles of 32
#define STG     12288               // elements per LDS stage (24 KB: A 8K + Bh 8K + Bl 8K)
#define DECAY   0.6f
#define THRESH  0.9f

typedef __attribute__((ext_vector_type(8))) short bf16x8;
typedef __attribute__((ext_vector_type(4))) float f32x4;

// pack 8 fp32 (two float4) -> 8 bf16 (uint4) by truncation; exact for {0,1}
#define PACK8(dstp, v0, v1)                                                                        \
    {                                                                                              \
        unsigned int p0 = __builtin_amdgcn_perm(__builtin_bit_cast(unsigned int, (v0).y),          \
                                                __builtin_bit_cast(unsigned int, (v0).x), 0x07060302u); \
        unsigned int p1 = __builtin_amdgcn_perm(__builtin_bit_cast(unsigned int, (v0).w),          \
                                                __builtin_bit_cast(unsigned int, (v0).z), 0x07060302u); \
        unsigned int p2 = __builtin_amdgcn_perm(__builtin_bit_cast(unsigned int, (v1).y),          \
                                                __builtin_bit_cast(unsigned int, (v1).x), 0x07060302u); \
        unsigned int p3 = __builtin_amdgcn_perm(__builtin_bit_cast(unsigned int, (v1).w),          \
                                                __builtin_bit_cast(unsigned int, (v1).z), 0x07060302u); \
        *(uint4*)(dstp) = make_uint4(p0, p1, p2, p3);                                              \
    }

// async global->LDS, 16B per lane, linear wave-contiguous LDS dest
#define GLL(g, l)                                                                                  \
    __builtin_amdgcn_global_load_lds((const __attribute__((address_space(1))) void*)(g),           \
                                     (__attribute__((address_space(3))) void*)(l), 16, 0, 0)

// ---------------------------------------------------------------------------
// W1 split-transpose body (shared by prep / prep_small):
// W1[784][1024] fp32 -> Th[1024][800] bf16 (hi), Tl[1024][800] bf16 (lo).
// ---------------------------------------------------------------------------
__device__ __forceinline__ void w1_split_body(const float* __restrict__ W1,
                                              unsigned short* __restrict__ Th,
                                              unsigned short* __restrict__ Tl,
                                              int b2, int t,
                                              unsigned short lh[32][33],
                                              unsigned short ll[32][33]) {
    const int nb = (b2 & 31) * 32;
    const int kb = (b2 >> 5) * 32;
    const int ln = t & 31, lk = t >> 5;
    #pragma unroll
    for (int i = 0; i < 4; ++i) {
        const int k = kb + lk + i * 8;
        const float w = (k < IN_DIM) ? W1[(size_t)k * HID_DIM + nb + ln] : 0.f;
        __hip_bfloat16 h = __float2bfloat16(w);
        float hf = __bfloat162float(h);
        __hip_bfloat16 l = __float2bfloat16(w - hf);
        lh[lk + i * 8][ln] = __builtin_bit_cast(unsigned short, h);
        ll[lk + i * 8][ln] = __builtin_bit_cast(unsigned short, l);
    }
    __syncthreads();
    const int o_n = t >> 3;
    const int o_k = (t & 7) * 4;
    ushort4 vh, vl;
    vh.x = lh[o_k + 0][o_n]; vh.y = lh[o_k + 1][o_n];
    vh.z = lh[o_k + 2][o_n]; vh.w = lh[o_k + 3][o_n];
    vl.x = ll[o_k + 0][o_n]; vl.y = ll[o_k + 1][o_n];
    vl.z = ll[o_k + 2][o_n]; vl.w = ll[o_k + 3][o_n];
    *(ushort4*)&Th[(size_t)(nb + o_n) * KPAD + kb + o_k] = vh;
    *(ushort4*)&Tl[(size_t)(nb + o_n) * KPAD + kb + o_k] = vl;
}

// ---------------------------------------------------------------------------
// prep (big-workspace path): X->bf16, W1 split, outu zero — one launch.
// ---------------------------------------------------------------------------
__global__ __launch_bounds__(256) void prep(const float* __restrict__ X,
                                            const float* __restrict__ W1,
                                            unsigned short* __restrict__ Xb,
                                            unsigned short* __restrict__ Th,
                                            unsigned short* __restrict__ Tl,
                                            float* __restrict__ outu) {
    __shared__ unsigned short lh[32][33];
    __shared__ unsigned short ll[32][33];
    const int bid = blockIdx.x;
    const int t   = threadIdx.x;

    if (bid < 10000) {
        const int gid = bid * 256 + t;           // 0 .. 2,559,999
        const int r   = gid / 100;
        const int c   = gid - r * 100;
        unsigned short* dst = Xb + (size_t)r * KPAD + c * 8;
        if (c < 98) {
            const float* s = X + (size_t)r * IN_DIM + c * 8;
            float4 v0 = *(const float4*)s, v1 = *(const float4*)(s + 4);
            PACK8(dst, v0, v1);
        } else {
            *(uint4*)dst = make_uint4(0u, 0u, 0u, 0u);
        }
    } else if (bid < 10800) {
        w1_split_body(W1, Th, Tl, bid - 10000, t, lh, ll);
    } else {
        float4* p = (float4*)outu;
        p[(bid - 10800) * 256 + t] = make_float4(0.f, 0.f, 0.f, 0.f);
    }
}

// prep_small (fallback path): W1 split + outu zero only (proven 3.3 MB ws use)
__global__ __launch_bounds__(256) void prep_small(const float* __restrict__ W1,
                                                  unsigned short* __restrict__ Th,
                                                  unsigned short* __restrict__ Tl,
                                                  float* __restrict__ outu) {
    __shared__ unsigned short lh[32][33];
    __shared__ unsigned short ll[32][33];
    const int bid = blockIdx.x;
    const int t   = threadIdx.x;
    if (bid < 800) {
        w1_split_body(W1, Th, Tl, bid, t, lh, ll);
    } else {
        float4* p = (float4*)outu;
        p[(bid - 800) * 256 + t] = make_float4(0.f, 0.f, 0.f, 0.f);
    }
}

// ---------------------------------------------------------------------------
// gemm1_pipe2: C[25600 x 1024] = Xb @ (Th + Tl), all-bf16 operands.
// 128x128 tile, BK=32, 4 waves x 64x64. Identical math/layout to the
// R2-verified gemm1_pipe; only the ring/occupancy changed:
//   2-stage x 24 KB ring (48 KB LDS) -> 3 blocks/CU (was 72 KB / 2 blocks).
// Per iter: [vmcnt(0) for stage k — issued one full compute phase earlier]
// [raw barrier] [STAGE k+1 into the other buffer] [ds_read frags] [MFMA].
// Safety: vmcnt BEFORE barrier => all waves' stage-k writes visible after;
// STAGE(k+1) AFTER barrier => ordered after all waves' frag reads of k-1
// from that same buffer.
// ---------------------------------------------------------------------------
__global__ __launch_bounds__(256, 3) void gemm1_pipe2(const unsigned short* __restrict__ Xb,
                                                      const unsigned short* __restrict__ Th,
                                                      const unsigned short* __restrict__ Tl,
                                                      float* __restrict__ C) {
    __shared__ unsigned short smem[2 * STG];   // 48 KB

    const int tid = threadIdx.x;
    const int bid = blockIdx.x;
    const int xcd = bid & 7;
    const int j_  = bid >> 3;                  // 0..199
    const int m0  = (xcd * 25 + (j_ >> 3)) * 128;
    const int n0  = (j_ & 7) * 128;

    const int lane = tid & 63, wv = tid >> 6;
    const int wm   = (wv & 1) * 64, wn = (wv >> 1) * 64;
    const int ml   = lane & 15, quad = lane >> 4;

    const int row  = tid >> 2;                 // 0..63
    const int slot = tid & 3;
    const int sOff = (slot ^ ((row >> 1) & 3)) * 8;   // f(row+64)==f(row)

    const unsigned short* gA0 = Xb + (size_t)(m0 + row)      * KPAD + sOff;
    const unsigned short* gA1 = Xb + (size_t)(m0 + row + 64) * KPAD + sOff;
    const unsigned short* gH0 = Th + (size_t)(n0 + row)      * KPAD + sOff;
    const unsigned short* gH1 = Th + (size_t)(n0 + row + 64) * KPAD + sOff;
    const unsigned short* gL0 = Tl + (size_t)(n0 + row)      * KPAD + sOff;
    const unsigned short* gL1 = Tl + (size_t)(n0 + row + 64) * KPAD + sOff;

#define STAGE(bf, it)                                                     \
    {                                                                     \
        unsigned short* b_ = smem + (bf) * STG;                           \
        const int k_ = (it) * 32;                                         \
        GLL(gA0 + k_, b_ + tid * 8);                                      \
        GLL(gA1 + k_, b_ + 2048 + tid * 8);                               \
        GLL(gH0 + k_, b_ + 4096 + tid * 8);                               \
        GLL(gH1 + k_, b_ + 6144 + tid * 8);                               \
        GLL(gL0 + k_, b_ + 8192 + tid * 8);                               \
        GLL(gL1 + k_, b_ + 10240 + tid * 8);                              \
    }

    f32x4 acc[4][4];
    #pragma unroll
    for (int i = 0; i < 4; ++i)
        #pragma unroll
        for (int j = 0; j < 4; ++j)
            acc[i][j] = (f32x4){0.f, 0.f, 0.f, 0.f};

    int offA[4], offB[4];
    #pragma unroll
    for (int i = 0; i < 4; ++i) {
        const int m = wm + i * 16 + ml;
        offA[i] = m * 32 + ((quad ^ ((m >> 1) & 3)) * 8);
    }
    #pragma unroll
    for (int j = 0; j < 4; ++j) {
        const int n = wn + j * 16 + ml;
        offB[j] = n * 32 + ((quad ^ ((n >> 1) & 3)) * 8);
    }

    // prologue: stage tile 0
    STAGE(0, 0);

    int buf = 0;
    for (int it = 0; it < NT; ++it) {
        // stage `it` was issued one full compute phase ago; drain remainder
        asm volatile("s_waitcnt vmcnt(0)" ::: "memory");
        __builtin_amdgcn_s_barrier();           // raw barrier: no extra drain
        asm volatile("" ::: "memory");

        // stage tile it+1 into the other buffer (its readers passed barrier)
        if (it + 1 < NT) STAGE(buf ^ 1, it + 1);

        const unsigned short* base = smem + buf * STG;
        bf16x8 af[4], bh[4], bl[4];
        #pragma unroll
        for (int i = 0; i < 4; ++i)
            af[i] = *(const bf16x8*)&base[offA[i]];
        #pragma unroll
        for (int j = 0; j < 4; ++j) {
            bh[j] = *(const bf16x8*)&base[4096 + offB[j]];
            bl[j] = *(const bf16x8*)&base[8192 + offB[j]];
        }

        __builtin_amdgcn_s_setprio(1);
        #pragma unroll
        for (int i = 0; i < 4; ++i)
            #pragma unroll
            for (int j = 0; j < 4; ++j) {
                acc[i][j] = __builtin_amdgcn_mfma_f32_16x16x32_bf16(af[i], bh[j], acc[i][j], 0, 0, 0);
                acc[i][j] = __builtin_amdgcn_mfma_f32_16x16x32_bf16(af[i], bl[j], acc[i][j], 0, 0, 0);
            }
        __builtin_amdgcn_s_setprio(0);

        buf ^= 1;
    }
#undef STAGE

    // epilogue: C/D layout col=lane&15, row=quad*4+reg
    #pragma unroll
    for (int i = 0; i < 4; ++i)
        #pragma unroll
        for (int j = 0; j < 4; ++j) {
            const int r0 = m0 + wm + i * 16 + quad * 4;
            const int c0 = n0 + wn + j * 16 + ml;
            #pragma unroll
            for (int r = 0; r < 4; ++r)
                C[(size_t)(r0 + r) * HID_DIM + c0] = acc[i][j][r];
        }
}

// ---------------------------------------------------------------------------
// gemm1_fallback: harness-verified R0 kernel (fp32 X, PACK8 in-kernel).
// Used only when ws is too small for Xb.
// ---------------------------------------------------------------------------
__global__ __launch_bounds__(256, 3) void gemm1_fallback(const float* __restrict__ X,
                                                         const unsigned short* __restrict__ Th,
                                                         const unsigned short* __restrict__ Tl,
                                                         float* __restrict__ C) {
    __shared__ unsigned short As[128 * 32];
    __shared__ unsigned short Bhs[128 * 32];
    __shared__ unsigned short Bls[128 * 32];

    const int tid = threadIdx.x;
    const int bid = blockIdx.x;
    const int xcd = bid & 7;
    const int j_  = bid >> 3;
    const int m0  = (xcd * 25 + (j_ >> 3)) * 128;
    const int n0  = (j_ & 7) * 128;

    const int lane = tid & 63, wv = tid >> 6;
    const int wm   = (wv & 1) * 64, wn = (wv >> 1) * 64;
    const int ml   = lane & 15, quad = lane >> 4;

    const int sr = tid >> 2;
    const int sc = tid & 3;
    const int f0 = (sr >> 1) & 3;
    const int w0 = sr * 32 + ((sc ^ f0) * 8);
    const int w1 = (sr + 64) * 32 + ((sc ^ f0) * 8);

    const float*          Xa = X  + (size_t)(m0 + sr)      * IN_DIM + sc * 8;
    const float*          Xc = X  + (size_t)(m0 + sr + 64) * IN_DIM + sc * 8;
    const unsigned short* Ha = Th + (size_t)(n0 + sr)      * KPAD   + sc * 8;
    const unsigned short* Hb = Th + (size_t)(n0 + sr + 64) * KPAD   + sc * 8;
    const unsigned short* La = Tl + (size_t)(n0 + sr)      * KPAD   + sc * 8;
    const unsigned short* Lb = Tl + (size_t)(n0 + sr + 64) * KPAD   + sc * 8;

    f32x4 acc[4][4];
    #pragma unroll
    for (int i = 0; i < 4; ++i)
        #pragma unroll
        for (int j = 0; j < 4; ++j)
            acc[i][j] = (f32x4){0.f, 0.f, 0.f, 0.f};

    float4 xa0 = *(const float4*)&Xa[0], xa1 = *(const float4*)&Xa[4];
    float4 xb0 = *(const float4*)&Xc[0], xb1 = *(const float4*)&Xc[4];
    uint4  vh0 = *(const uint4*)&Ha[0],  vh1 = *(const uint4*)&Hb[0];
    uint4  vl0 = *(const uint4*)&La[0],  vl1 = *(const uint4*)&Lb[0];
    PACK8(&As[w0], xa0, xa1);
    PACK8(&As[w1], xb0, xb1);
    *(uint4*)&Bhs[w0] = vh0;  *(uint4*)&Bhs[w1] = vh1;
    *(uint4*)&Bls[w0] = vl0;  *(uint4*)&Bls[w1] = vl1;
    __syncthreads();

    for (int it = 0; it < NT; ++it) {
        bf16x8 af[4], bh[4], bl[4];
        #pragma unroll
        for (int i = 0; i < 4; ++i) {
            const int m = wm + i * 16 + ml;
            af[i] = *(const bf16x8*)&As[m * 32 + ((quad ^ ((m >> 1) & 3)) * 8)];
        }
        #pragma unroll
        for (int j = 0; j < 4; ++j) {
            const int n   = wn + j * 16 + ml;
            const int idx = n * 32 + ((quad ^ ((n >> 1) & 3)) * 8);
            bh[j] = *(const bf16x8*)&Bhs[idx];
            bl[j] = *(const bf16x8*)&Bls[idx];
        }

        const bool have_next = (it + 1 < NT);
        if (have_next) {
            const int kt = (it + 1) * 32;
            const int c0 = kt + sc * 8;
            const bool v0 = (c0 < IN_DIM), v1 = (c0 + 4 < IN_DIM);
            xa0 = v0 ? *(const float4*)&Xa[kt]     : make_float4(0.f, 0.f, 0.f, 0.f);
            xa1 = v1 ? *(const float4*)&Xa[kt + 4] : make_float4(0.f, 0.f, 0.f, 0.f);
            xb0 = v0 ? *(const float4*)&Xc[kt]     : make_float4(0.f, 0.f, 0.f, 0.f);
            xb1 = v1 ? *(const float4*)&Xc[kt + 4] : make_float4(0.f, 0.f, 0.f, 0.f);
            vh0 = *(const uint4*)&Ha[kt];  vh1 = *(const uint4*)&Hb[kt];
            vl0 = *(const uint4*)&La[kt];  vl1 = *(const uint4*)&Lb[kt];
        }

        #pragma unroll
        for (int i = 0; i < 4; ++i)
            #pragma unroll
            for (int j = 0; j < 4; ++j) {
                acc[i][j] = __builtin_amdgcn_mfma_f32_16x16x32_bf16(af[i], bh[j], acc[i][j], 0, 0, 0);
                acc[i][j] = __builtin_amdgcn_mfma_f32_16x16x32_bf16(af[i], bl[j], acc[i][j], 0, 0, 0);
            }

        __syncthreads();
        if (have_next) {
            PACK8(&As[w0], xa0, xa1);
            PACK8(&As[w1], xb0, xb1);
            *(uint4*)&Bhs[w0] = vh0;  *(uint4*)&Bhs[w1] = vh1;
            *(uint4*)&Bls[w0] = vl0;  *(uint4*)&Bls[w1] = vl1;
            __syncthreads();
        }
    }

    #pragma unroll
    for (int i = 0; i < 4; ++i)
        #pragma unroll
        for (int j = 0; j < 4; ++j) {
            const int r0 = m0 + wm + i * 16 + quad * 4;
            const int c0 = n0 + wn + j * 16 + ml;
            #pragma unroll
            for (int r = 0; r < 4; ++r)
                C[(size_t)(r0 + r) * HID_DIM + c0] = acc[i][j][r];
        }
}

// ---------------------------------------------------------------------------
// LIF1 fused with GEMM2 scatter. float2/thread: 131072 threads = 2 waves/SIMD
// for better latency overlap of the serial t-scan. Rare-spike atomic scatter.
// ---------------------------------------------------------------------------
__global__ __launch_bounds__(256) void lif1_fused(float* __restrict__ hid,
                                                  const float* __restrict__ W2,
                                                  float* __restrict__ outu) {
    const int idx = blockIdx.x * blockDim.x + threadIdx.x;   // 0..131071
    float2* h2 = (float2*)hid;
    const int stride2 = (BATCH * HID_DIM) / 2;               // 131072
    const int b  = idx >> 9;
    const int h0 = (idx * 2) & 1023;

    float2 mem = make_float2(0.f, 0.f);
    float2 u[4];
    #pragma unroll
    for (int c = 0; c < 4; ++c) u[c] = h2[c * stride2 + idx];

    for (int t = 0; t < T_STEPS; t += 4) {
        float2 nu[4];
        if (t + 4 < T_STEPS) {
            #pragma unroll
            for (int c = 0; c < 4; ++c) nu[c] = h2[(t + 4 + c) * stride2 + idx];
        }
        #pragma unroll
        for (int c = 0; c < 4; ++c) {
            float2 uu = u[c];
            float2 s;
            mem.x = mem.x * DECAY + uu.x; s.x = (mem.x >= THRESH) ? 1.f : 0.f; mem.x -= s.x * THRESH;
            mem.y = mem.y * DECAY + uu.y; s.y = (mem.y >= THRESH) ? 1.f : 0.f; mem.y -= s.y * THRESH;
            h2[(t + c) * stride2 + idx] = s;
            if (s.x + s.y > 0.f) {                           // ~never taken
                float* od = outu + (size_t)(t + c) * (BATCH * OUT_DIM) + b * OUT_DIM;
                #pragma unroll
                for (int e = 0; e < 2; ++e) {
                    const float sv = (&s.x)[e];
                    if (sv != 0.f) {
                        const float* w = W2 + (size_t)(h0 + e) * OUT_DIM;
                        #pragma unroll
                        for (int o = 0; o < OUT_DIM; ++o) atomicAdd(&od[o], w[o]);
                    }
                }
            }
        }
        #pragma unroll
        for (int c = 0; c < 4; ++c) u[c] = nu[c];
    }
}

// ---------------------------------------------------------------------------
// LIF2: scan output membranes in place; 4-deep prefetch hides serial latency.
// ---------------------------------------------------------------------------
__global__ __launch_bounds__(256) void lif2(float* __restrict__ outp) {
    const int n = blockIdx.x * blockDim.x + threadIdx.x;
    const int stride = BATCH * OUT_DIM;                      // 2560
    if (n >= stride) return;
    float mem = 0.f;
    float u[4];
    #pragma unroll
    for (int c = 0; c < 4; ++c) u[c] = outp[c * stride + n];
    for (int t = 0; t < T_STEPS; t += 4) {
        float nu[4];
        if (t + 4 < T_STEPS) {
            #pragma unroll
            for (int c = 0; c < 4; ++c) nu[c] = outp[(t + 4 + c) * stride + n];
        }
        #pragma unroll
        for (int c = 0; c < 4; ++c) {
            mem = mem * DECAY + u[c];
            float s = (mem >= THRESH) ? 1.f : 0.f;
            mem -= s * THRESH;
            outp[(t + c) * stride + n] = s;
        }
        #pragma unroll
        for (int c = 0; c < 4; ++c) u[c] = nu[c];
    }
}

extern "C" void kernel_launch(void* const* d_in, const int* in_sizes, int n_in,
                              void* d_out, int out_size, void* d_ws, size_t ws_size,
                              hipStream_t stream) {
    const float* x  = (const float*)d_in[0];   // [T, B, I]
    const float* W1 = (const float*)d_in[1];   // [I, H]
    const float* W2 = (const float*)d_in[2];   // [H, O]
    float* out  = (float*)d_out;
    float* hid  = out;                                    // [T*B, H]
    float* outu = out + (size_t)M_ROWS * HID_DIM;         // [T*B, O]

    unsigned short* Th = (unsigned short*)d_ws;           // [1024][800] bf16 (1.6 MB)
    unsigned short* Tl = Th + (size_t)HID_DIM * KPAD;     // [1024][800] bf16 (1.6 MB)
    unsigned short* Xb = Tl + (size_t)HID_DIM * KPAD;     // [25600][800] bf16 (41 MB)

    const size_t ws_needed_big =
        (size_t)2 * HID_DIM * KPAD * sizeof(unsigned short) +
        (size_t)M_ROWS * KPAD * sizeof(unsigned short);   // 44.24 MB

    if (ws_size >= ws_needed_big) {
        // fast path: all-bf16 GEMM, 2-stage GLL ring, 3 blocks/CU
        prep<<<11050, 256, 0, stream>>>(x, W1, Xb, Th, Tl, outu);
        gemm1_pipe2<<<1600, 256, 0, stream>>>(Xb, Th, Tl, hid);
    } else {
        // proven-safe path: 3.3 MB workspace only
        prep_small<<<1050, 256, 0, stream>>>(W1, Th, Tl, outu);
        gemm1_fallback<<<1600, 256, 0, stream>>>(x, Th, Tl, hid);
    }

    lif1_fused<<<(BATCH * HID_DIM / 2) / 256, 256, 0, stream>>>(hid, W2, outu);

    lif2<<<(BATCH * OUT_DIM + 255) / 256, 256, 0, stream>>>(outu);
}